// Round 1
// baseline (593.853 us; speedup 1.0000x reference)
//
#include <hip/hip_runtime.h>
#include <hip/hip_bf16.h>
#include <stdint.h>

typedef short v8s __attribute__((ext_vector_type(8)));
typedef short v4s __attribute__((ext_vector_type(4)));
typedef float v4f __attribute__((ext_vector_type(4)));

constexpr int S    = 2048;
constexpr int D    = 128;
constexpr int QBLK = 64;   // 4 waves x 16 rows
constexpr int KVBLK = 64;

#define LOG2E_F 1.44269504f

__device__ __forceinline__ unsigned short f2bf(float x) {
    union { float f; uint32_t u; } v; v.f = x;
    uint32_t r = v.u + 0x7FFFu + ((v.u >> 16) & 1u);   // RNE
    return (unsigned short)(r >> 16);
}

__global__ __launch_bounds__(256, 2)
void fattn_kernel(const float* __restrict__ Qg,
                  const float* __restrict__ Kg,
                  const float* __restrict__ Vg,
                  float* __restrict__ Og)
{
    // K tile [kv][d] bf16, swizzle: d-group8 ^= (kv&7)
    __shared__ __align__(16) short Ks[KVBLK * D];
    // V^T tile [d][kv] bf16, swizzle: kv ^= ((d&7)<<3) ^ (((d>>3)&3)<<4)
    __shared__ __align__(16) short Vt[D * KVBLK];
    // per-wave P [q][kv] bf16, swizzle: kv-group8 ^= (q&7)
    __shared__ __align__(16) short Pl[4][16 * KVBLK];

    const int tid  = threadIdx.x;
    const int wave = tid >> 6;
    const int lane = tid & 63;
    const int l15  = lane & 15;
    const int lg   = lane >> 4;

    const int bh = blockIdx.y;
    const int q0 = blockIdx.x * QBLK + wave * 16;
    const size_t base = (size_t)bh * S * D;

    const float SCALE = LOG2E_F * LOG2E_F * 0.08838834764831845f; // log2e^2 / sqrt(128)

    // ---- Q fragments (MFMA B-operand layout): lane holds Q[q0+l15][dc*32 + lg*8 + j]
    v8s qf[4];
    {
        const float* qp = Qg + base + (size_t)(q0 + l15) * D + lg * 8;
        #pragma unroll
        for (int dc = 0; dc < 4; ++dc) {
            float4 a = *(const float4*)(qp + dc * 32);
            float4 b = *(const float4*)(qp + dc * 32 + 4);
            v8s t;
            t[0] = (short)f2bf(a.x * SCALE); t[1] = (short)f2bf(a.y * SCALE);
            t[2] = (short)f2bf(a.z * SCALE); t[3] = (short)f2bf(a.w * SCALE);
            t[4] = (short)f2bf(b.x * SCALE); t[5] = (short)f2bf(b.y * SCALE);
            t[6] = (short)f2bf(b.z * SCALE); t[7] = (short)f2bf(b.w * SCALE);
            qf[dc] = t;
        }
    }

    const v4f zf = {0.f, 0.f, 0.f, 0.f};
    v4f o[8];   // O^T accum: o[ds][r] = O[q=l15][d = ds*16 + lg*4 + r]
    #pragma unroll
    for (int i = 0; i < 8; ++i) o[i] = zf;
    float m_run = -1e30f;
    float l_run = 0.f;

    for (int kv0 = 0; kv0 < S; kv0 += KVBLK) {
        __syncthreads();

        // ---- stage K tile (coalesced f32 reads -> bf16 b128 LDS writes)
        #pragma unroll
        for (int i = 0; i < 4; ++i) {
            int g   = i * 256 + tid;
            int row = g >> 4;        // 0..63
            int c   = g & 15;        // 8-elem column group
            const float* kp = Kg + base + (size_t)(kv0 + row) * D + c * 8;
            float4 a = *(const float4*)kp;
            float4 b = *(const float4*)(kp + 4);
            v8s t;
            t[0] = (short)f2bf(a.x); t[1] = (short)f2bf(a.y);
            t[2] = (short)f2bf(a.z); t[3] = (short)f2bf(a.w);
            t[4] = (short)f2bf(b.x); t[5] = (short)f2bf(b.y);
            t[6] = (short)f2bf(b.z); t[7] = (short)f2bf(b.w);
            *(v8s*)(&Ks[row * D + ((c ^ (row & 7)) << 3)]) = t;
        }

        // ---- stage V^T (coalesced f32 reads -> swizzled scalar bf16 writes, conflict-free)
        {
            int kv = tid >> 2;       // 0..63
            int dg = tid & 3;        // 8-elem d group within 32-chunk
            const float* vp = Vg + base + (size_t)(kv0 + kv) * D + dg * 8;
            #pragma unroll
            for (int s4 = 0; s4 < 4; ++s4) {
                float4 a = *(const float4*)(vp + s4 * 32);
                float4 b = *(const float4*)(vp + s4 * 32 + 4);
                float vv[8] = {a.x, a.y, a.z, a.w, b.x, b.y, b.z, b.w};
                #pragma unroll
                for (int j = 0; j < 8; ++j) {
                    int d   = s4 * 32 + dg * 8 + j;
                    int kvs = kv ^ ((d & 7) << 3) ^ (((d >> 3) & 3) << 4);
                    Vt[d * KVBLK + kvs] = (short)vv[j] * 0 + (short)f2bf(vv[j]);
                }
            }
        }
        __syncthreads();

        // ---- QK^T (swapped): S^T[kv][q] = K·Q^T, q lane-local in l15
        v4f sc[4];
        #pragma unroll
        for (int t = 0; t < 4; ++t) sc[t] = zf;
        #pragma unroll
        for (int t = 0; t < 4; ++t) {
            int row = t * 16 + l15;
            #pragma unroll
            for (int dc = 0; dc < 4; ++dc) {
                int cg = dc * 4 + lg;
                v8s kf = *(const v8s*)(&Ks[row * D + ((cg ^ (row & 7)) << 3)]);
                sc[t] = __builtin_amdgcn_mfma_f32_16x16x32_bf16(kf, qf[dc], sc[t], 0, 0, 0);
            }
        }

        // ---- online softmax over kv (lane holds kv = t*16 + lg*4 + r for q = l15)
        float tm = sc[0][0];
        #pragma unroll
        for (int t = 0; t < 4; ++t)
            #pragma unroll
            for (int r = 0; r < 4; ++r) tm = fmaxf(tm, sc[t][r]);
        tm = fmaxf(tm, __shfl_xor(tm, 16));
        tm = fmaxf(tm, __shfl_xor(tm, 32));
        float m_new = fmaxf(m_run, tm);
        float alpha = exp2f(m_run - m_new);

        float tsum = 0.f;
        v4s pv[4];
        #pragma unroll
        for (int t = 0; t < 4; ++t) {
            #pragma unroll
            for (int r = 0; r < 4; ++r) {
                float p = exp2f(sc[t][r] - m_new);
                tsum += p;
                pv[t][r] = (short)f2bf(p);
            }
        }
        tsum += __shfl_xor(tsum, 16);
        tsum += __shfl_xor(tsum, 32);
        l_run = l_run * alpha + tsum;
        m_run = m_new;
        #pragma unroll
        for (int i = 0; i < 8; ++i) o[i] = o[i] * alpha;

        // ---- write P (bf16) to per-wave LDS in [q][kv] swizzled layout
        short* pw = &Pl[wave][0];
        #pragma unroll
        for (int t = 0; t < 4; ++t) {
            int kvb = t * 16 + lg * 4;
            int idx = l15 * KVBLK + (((kvb >> 3) ^ (l15 & 7)) << 3) + (kvb & 7);
            *(v4s*)(&pw[idx]) = pv[t];
        }
        __syncthreads();

        // ---- PV: O^T += V^T · P^T
        v8s pf[2];
        #pragma unroll
        for (int h = 0; h < 2; ++h) {
            int kvg = h * 4 + lg;
            pf[h] = *(const v8s*)(&pw[l15 * KVBLK + ((kvg ^ (l15 & 7)) << 3)]);
        }
        #pragma unroll
        for (int ds = 0; ds < 8; ++ds) {
            int d  = ds * 16 + l15;
            int sw = ((d & 7) << 3) ^ (((d >> 3) & 3) << 4);
            #pragma unroll
            for (int h = 0; h < 2; ++h) {
                v8s vf = *(const v8s*)(&Vt[d * KVBLK + ((h * 32 + lg * 8) ^ sw)]);
                o[ds] = __builtin_amdgcn_mfma_f32_16x16x32_bf16(vf, pf[h], o[ds], 0, 0, 0);
            }
        }
    }

    // ---- epilogue: normalize, store f32 (64B-contiguous float4 per 4-lane group)
    float inv = 1.f / l_run;
    float* op = Og + base + (size_t)(q0 + l15) * D;
    #pragma unroll
    for (int ds = 0; ds < 8; ++ds) {
        float4 w;
        w.x = o[ds][0] * inv; w.y = o[ds][1] * inv;
        w.z = o[ds][2] * inv; w.w = o[ds][3] * inv;
        *(float4*)(op + ds * 16 + lg * 4) = w;
    }
}

extern "C" void kernel_launch(void* const* d_in, const int* in_sizes, int n_in,
                              void* d_out, int out_size, void* d_ws, size_t ws_size,
                              hipStream_t stream) {
    const float* Q = (const float*)d_in[0];
    const float* K = (const float*)d_in[1];
    const float* V = (const float*)d_in[2];
    float* O = (float*)d_out;
    dim3 grid(S / QBLK, 64);   // 32 q-tiles x (B*H)=64
    dim3 block(256);
    fattn_kernel<<<grid, block, 0, stream>>>(Q, K, V, O);
}

// Round 2
// 460.680 us; speedup vs baseline: 1.2891x; 1.2891x over previous
//
#include <hip/hip_runtime.h>
#include <hip/hip_bf16.h>
#include <stdint.h>

typedef short v8s __attribute__((ext_vector_type(8)));
typedef short v4s __attribute__((ext_vector_type(4)));
typedef float v4f __attribute__((ext_vector_type(4)));

constexpr int S     = 2048;
constexpr int D     = 128;
constexpr int QBLK  = 64;    // 4 waves x 16 q-rows
constexpr int KVBLK = 64;
constexpr int NT    = S / KVBLK;   // 32
constexpr int BH    = 64;          // batch*heads

#define LOG2E_F 1.44269504f

__device__ __forceinline__ unsigned short f2bf(float x) {
    union { float f; uint32_t u; } v; v.f = x;
    uint32_t r = v.u + 0x7FFFu + ((v.u >> 16) & 1u);   // RNE
    return (unsigned short)(r >> 16);
}

__device__ __forceinline__ void gload_lds16(const void* g, void* l) {
    __builtin_amdgcn_global_load_lds(
        (const __attribute__((address_space(1))) unsigned int*)g,
        (__attribute__((address_space(3))) unsigned int*)l,
        16, 0, 0);
}

// ---------------- prepass 1: K f32 -> bf16, same layout [bh][kv][d] ----------
__global__ __launch_bounds__(256)
void kconv_kernel(const float* __restrict__ src, short* __restrict__ dst) {
    size_t i = ((size_t)blockIdx.x * 256 + threadIdx.x) * 8;
    float4 a = *(const float4*)(src + i);
    float4 b = *(const float4*)(src + i + 4);
    v8s t;
    t[0] = (short)f2bf(a.x); t[1] = (short)f2bf(a.y);
    t[2] = (short)f2bf(a.z); t[3] = (short)f2bf(a.w);
    t[4] = (short)f2bf(b.x); t[5] = (short)f2bf(b.y);
    t[6] = (short)f2bf(b.z); t[7] = (short)f2bf(b.w);
    *(v8s*)(dst + i) = t;
}

// ---------------- prepass 2: V f32 [bh][kv][d] -> bf16 transposed [bh][d][kv] -
__global__ __launch_bounds__(256)
void vtrans_kernel(const float* __restrict__ Vg, short* __restrict__ VtG) {
    // per-row xor swizzle (elem-level, flips kv bits 3..5) keeps b128 reads conflict-free
    __shared__ __align__(16) short T[D * KVBLK];
    const int bh = blockIdx.y;
    const int kv0 = blockIdx.x * KVBLK;
    const float* vp = Vg + ((size_t)bh * S + kv0) * D;
    const int kv = threadIdx.x >> 2;
    const int dg = threadIdx.x & 3;
    #pragma unroll
    for (int s4 = 0; s4 < 4; ++s4) {
        float4 a = *(const float4*)(vp + (size_t)kv * D + s4 * 32 + dg * 8);
        float4 b = *(const float4*)(vp + (size_t)kv * D + s4 * 32 + dg * 8 + 4);
        float vv[8] = {a.x, a.y, a.z, a.w, b.x, b.y, b.z, b.w};
        #pragma unroll
        for (int j = 0; j < 8; ++j) {
            int d = s4 * 32 + dg * 8 + j;
            T[d * KVBLK + (kv ^ ((d & 7) << 3))] = (short)f2bf(vv[j]);
        }
    }
    __syncthreads();
    // write rows of VtG: 8 x 16B chunks per d-row
    const int s = threadIdx.x & 7;
    #pragma unroll
    for (int p = 0; p < 4; ++p) {
        int d = p * 32 + (threadIdx.x >> 3);
        v8s w = *(const v8s*)(&T[d * KVBLK + ((s ^ (d & 7)) << 3)]);
        *(v8s*)(VtG + (size_t)bh * D * S + (size_t)d * S + kv0 + s * 8) = w;
    }
}

// ---------------- main fused attention -------------------------------------
__global__ __launch_bounds__(256, 2)
void fattn_kernel(const float* __restrict__ Qg,
                  const short* __restrict__ Kb,
                  const short* __restrict__ Vb,   // transposed [bh][d][kv]
                  float* __restrict__ Og)
{
    __shared__ __align__(16) short Ks[2][KVBLK * D];   // [kv][d], dgrp8 ^= kv&7
    __shared__ __align__(16) short Vt[2][D * KVBLK];   // [d][kv], kv ^= ((d&7)<<3)^(((d>>3)&3)<<4)
    __shared__ __align__(16) short Pl[4][16 * KVBLK];  // per-wave P, kvgrp8 ^= q&7

    const int tid  = threadIdx.x;
    const int wave = tid >> 6;
    const int lane = tid & 63;
    const int l15  = lane & 15;
    const int lg   = lane >> 4;

    // XCD-aware bijective swizzle: each XCD owns 8 consecutive bh values
    const int bid = blockIdx.x;
    const int swz = ((bid & 7) << 8) | (bid >> 3);
    const int bh  = swz >> 5;
    const int qt  = swz & 31;
    const int q0  = qt * QBLK + wave * 16;
    const size_t base = (size_t)bh * S * D;

    const float SCALE = LOG2E_F * LOG2E_F * 0.08838834764831845f; // log2e^2/sqrt(128)

    // ---- Q fragments (MFMA B-operand): lane holds Q[q0+l15][dc*32+lg*8+j]
    v8s qf[4];
    {
        const float* qp = Qg + base + (size_t)(q0 + l15) * D + lg * 8;
        #pragma unroll
        for (int dc = 0; dc < 4; ++dc) {
            float4 a = *(const float4*)(qp + dc * 32);
            float4 b = *(const float4*)(qp + dc * 32 + 4);
            v8s t;
            t[0] = (short)f2bf(a.x * SCALE); t[1] = (short)f2bf(a.y * SCALE);
            t[2] = (short)f2bf(a.z * SCALE); t[3] = (short)f2bf(a.w * SCALE);
            t[4] = (short)f2bf(b.x * SCALE); t[5] = (short)f2bf(b.y * SCALE);
            t[6] = (short)f2bf(b.z * SCALE); t[7] = (short)f2bf(b.w * SCALE);
            qf[dc] = t;
        }
    }

    const v4f zf = {0.f, 0.f, 0.f, 0.f};
    v4f o[8];
    #pragma unroll
    for (int i = 0; i < 8; ++i) o[i] = zf;
    float m_run = -1e30f;
    float l_run = 0.f;

    // ---- async stage of one KV tile into buffer `buf`
    auto stage = [&](int buf, int kv0) {
        #pragma unroll
        for (int i = 0; i < 4; ++i) {          // K: 4 rows per instr
            int rb  = wave * 4 + i;            // 16 row-blocks
            int row = rb * 4 + (lane >> 4);
            int s   = lane & 15;
            const short* src = Kb + base + (size_t)(kv0 + row) * D + ((s ^ (row & 7)) << 3);
            gload_lds16(src, &Ks[buf][rb * 512]);
        }
        #pragma unroll
        for (int i = 0; i < 4; ++i) {          // V: 8 d-rows per instr
            int rb = wave * 4 + i;
            int d  = rb * 8 + (lane >> 3);
            int s  = lane & 7;
            int sz = (d & 7) ^ (((d >> 3) & 3) << 1);   // slot-level swizzle
            const short* src = Vb + base + (size_t)d * S + kv0 + ((s ^ sz) << 3);
            gload_lds16(src, &Vt[buf][rb * 512]);
        }
    };

    stage(0, 0);
    __syncthreads();   // drains vmcnt(0): buf0 ready

    for (int it = 0; it < NT; ++it) {
        const int c = it & 1;
        if (it + 1 < NT) stage(c ^ 1, (it + 1) * KVBLK);   // prefetch under compute

        const short* ks = &Ks[c][0];
        const short* vt = &Vt[c][0];

        // ---- QK^T (swapped): S^T[kv][q], q lane-local in l15
        v4f sc[4];
        #pragma unroll
        for (int t = 0; t < 4; ++t) sc[t] = zf;
        __builtin_amdgcn_s_setprio(1);
        #pragma unroll
        for (int t = 0; t < 4; ++t) {
            int row = t * 16 + l15;
            #pragma unroll
            for (int dc = 0; dc < 4; ++dc) {
                int cg = dc * 4 + lg;
                v8s kf = *(const v8s*)(&ks[row * D + ((cg ^ (row & 7)) << 3)]);
                sc[t] = __builtin_amdgcn_mfma_f32_16x16x32_bf16(kf, qf[dc], sc[t], 0, 0, 0);
            }
        }
        __builtin_amdgcn_s_setprio(0);

        // ---- online softmax (lane holds kv = t*16+lg*4+r for q-row l15)
        float tm = sc[0][0];
        #pragma unroll
        for (int t = 0; t < 4; ++t)
            #pragma unroll
            for (int r = 0; r < 4; ++r) tm = fmaxf(tm, sc[t][r]);
        tm = fmaxf(tm, __shfl_xor(tm, 16));
        tm = fmaxf(tm, __shfl_xor(tm, 32));
        float m_new = fmaxf(m_run, tm);
        float alpha = exp2f(m_run - m_new);

        float tsum = 0.f;
        v4s pv[4];
        #pragma unroll
        for (int t = 0; t < 4; ++t) {
            #pragma unroll
            for (int r = 0; r < 4; ++r) {
                float p = exp2f(sc[t][r] - m_new);
                tsum += p;
                pv[t][r] = (short)f2bf(p);
            }
        }
        tsum += __shfl_xor(tsum, 16);
        tsum += __shfl_xor(tsum, 32);
        l_run = l_run * alpha + tsum;
        m_run = m_new;
        #pragma unroll
        for (int i = 0; i < 8; ++i) o[i] = o[i] * alpha;

        // ---- P round-trip through per-wave LDS (no block barrier needed)
        short* pw = &Pl[wave][0];
        #pragma unroll
        for (int t = 0; t < 4; ++t) {
            int kvb = t * 16 + lg * 4;
            int idx = l15 * KVBLK + (((kvb >> 3) ^ (l15 & 7)) << 3) + (kvb & 7);
            *(v4s*)(&pw[idx]) = pv[t];
        }
        v8s pf[2];
        #pragma unroll
        for (int h = 0; h < 2; ++h) {
            int kvg = h * 4 + lg;
            pf[h] = *(const v8s*)(&pw[l15 * KVBLK + ((kvg ^ (l15 & 7)) << 3)]);
        }

        // ---- PV: O^T += V^T · P^T
        __builtin_amdgcn_s_setprio(1);
        #pragma unroll
        for (int ds = 0; ds < 8; ++ds) {
            int d  = ds * 16 + l15;
            int sw = ((d & 7) << 3) ^ (((d >> 3) & 3) << 4);
            #pragma unroll
            for (int h = 0; h < 2; ++h) {
                v8s vf = *(const v8s*)(&vt[d * KVBLK + ((h * 32 + lg * 8) ^ sw)]);
                o[ds] = __builtin_amdgcn_mfma_f32_16x16x32_bf16(vf, pf[h], o[ds], 0, 0, 0);
            }
        }
        __builtin_amdgcn_s_setprio(0);

        __syncthreads();   // drains prefetch (vmcnt 0) + buffer-reuse barrier
    }

    // ---- epilogue
    float inv = 1.f / l_run;
    float* op = Og + base + (size_t)(q0 + l15) * D;
    #pragma unroll
    for (int ds = 0; ds < 8; ++ds) {
        float4 w;
        w.x = o[ds][0] * inv; w.y = o[ds][1] * inv;
        w.z = o[ds][2] * inv; w.w = o[ds][3] * inv;
        *(float4*)(op + ds * 16 + lg * 4) = w;
    }
}

extern "C" void kernel_launch(void* const* d_in, const int* in_sizes, int n_in,
                              void* d_out, int out_size, void* d_ws, size_t ws_size,
                              hipStream_t stream) {
    const float* Q = (const float*)d_in[0];
    const float* K = (const float*)d_in[1];
    const float* V = (const float*)d_in[2];
    float* O = (float*)d_out;

    short* Kb  = (short*)d_ws;                       // 33.55 MB
    short* VtG = Kb + (size_t)BH * S * D;            // 33.55 MB

    // prepass: K convert, V transpose+convert
    kconv_kernel<<<dim3(BH * S * D / (256 * 8)), dim3(256), 0, stream>>>(K, Kb);
    vtrans_kernel<<<dim3(S / KVBLK, BH), dim3(256), 0, stream>>>(V, VtG);

    // main kernel: 1D grid with XCD swizzle
    fattn_kernel<<<dim3(BH * S / QBLK), dim3(256), 0, stream>>>(Q, Kb, VtG, O);
}

// Round 4
// 393.559 us; speedup vs baseline: 1.5089x; 1.1705x over previous
//
#include <hip/hip_runtime.h>
#include <hip/hip_bf16.h>
#include <stdint.h>

typedef short v8s __attribute__((ext_vector_type(8)));
typedef float v16f __attribute__((ext_vector_type(16)));
typedef unsigned int u32;

constexpr int S = 2048, D = 128, KVBLK = 64, NT = S / KVBLK, BH = 64;
constexpr int QW = 32, WAVES = 8, QBLK = QW * WAVES;   // 256 q-rows/block

#define LOG2E_F 1.44269504f

__device__ __forceinline__ unsigned short f2bf(float x) {
    union { float f; uint32_t u; } v; v.f = x;
    uint32_t r = v.u + 0x7FFFu + ((v.u >> 16) & 1u);   // RNE
    return (unsigned short)(r >> 16);
}
__device__ __forceinline__ u32 cvtpk(float lo, float hi) {
    u32 r; asm("v_cvt_pk_bf16_f32 %0, %1, %2" : "=v"(r) : "v"(lo), "v"(hi)); return r;
}
__device__ __forceinline__ void gload_lds16(const void* g, void* l) {
    __builtin_amdgcn_global_load_lds(
        (const __attribute__((address_space(1))) unsigned int*)g,
        (__attribute__((address_space(3))) unsigned int*)l, 16, 0, 0);
}

// ---- fused prepass: K f32->bf16 [bh][kv][d]; V f32 -> bf16 transposed [bh][d][kv]
__global__ __launch_bounds__(256)
void prep_kernel(const float* __restrict__ Kg, const float* __restrict__ Vg,
                 short* __restrict__ Kb, short* __restrict__ VtG)
{
    __shared__ __align__(16) short T[D * KVBLK];
    const int bh = blockIdx.y, kv0 = blockIdx.x * KVBLK;
    const int tid = threadIdx.x;
    {   // K convert (streaming)
        const float* kp = Kg + ((size_t)bh * S + kv0) * D;
        short* kb = Kb + ((size_t)bh * S + kv0) * D;
        #pragma unroll
        for (int i = 0; i < 4; ++i) {
            int e = (i * 256 + tid) * 8;
            float4 a = *(const float4*)(kp + e), b = *(const float4*)(kp + e + 4);
            v8s t;
            t[0] = f2bf(a.x); t[1] = f2bf(a.y); t[2] = f2bf(a.z); t[3] = f2bf(a.w);
            t[4] = f2bf(b.x); t[5] = f2bf(b.y); t[6] = f2bf(b.z); t[7] = f2bf(b.w);
            *(v8s*)(kb + e) = t;
        }
    }
    {   // V transpose via LDS (elem swizzle kv ^= (d&7)<<3 keeps b128 reads clean)
        const float* vp = Vg + ((size_t)bh * S + kv0) * D;
        const int kv = tid >> 2, dg = tid & 3;
        #pragma unroll
        for (int s4 = 0; s4 < 4; ++s4) {
            float4 a = *(const float4*)(vp + (size_t)kv * D + s4 * 32 + dg * 8);
            float4 b = *(const float4*)(vp + (size_t)kv * D + s4 * 32 + dg * 8 + 4);
            float vv[8] = {a.x, a.y, a.z, a.w, b.x, b.y, b.z, b.w};
            #pragma unroll
            for (int j = 0; j < 8; ++j) {
                int d = s4 * 32 + dg * 8 + j;
                T[d * KVBLK + (kv ^ ((d & 7) << 3))] = (short)f2bf(vv[j]);
            }
        }
        __syncthreads();
        const int s = tid & 7;
        #pragma unroll
        for (int p = 0; p < 4; ++p) {
            int d = p * 32 + (tid >> 3);
            v8s w = *(const v8s*)(&T[d * KVBLK + ((s ^ (d & 7)) << 3)]);
            *(v8s*)(VtG + (size_t)bh * D * S + (size_t)d * S + kv0 + s * 8) = w;
        }
    }
}

// ---- main fused attention: 8 waves x 32 q-rows, 32x32x16 MFMA, dbuf LDS -----
__global__ __launch_bounds__(512, 2)
void fattn_kernel(const float* __restrict__ Qg, const short* __restrict__ Kb,
                  const short* __restrict__ Vb, float* __restrict__ Og)
{
    __shared__ __align__(16) short Ks[2][KVBLK * D];   // [kv][d], slot16B ^= kv&7
    __shared__ __align__(16) short Vt[2][D * KVBLK];   // [d][kv], slot16B ^= d&7

    const int tid = threadIdx.x, wave = tid >> 6, lane = tid & 63;
    const int l31 = lane & 31, h = lane >> 5;

    // XCD swizzle: head bh lands on XCD bh&7; 8 q-blocks of a head share the XCD
    const int bid = blockIdx.x;
    const int bh = (bid & 7) | ((bid >> 6) << 3);
    const int qt = (bid >> 3) & 7;
    const int q0 = qt * QBLK + wave * QW;
    const size_t base = (size_t)bh * S * D;

    const float SCALE = LOG2E_F * LOG2E_F * 0.08838834764831845f; // log2e^2/sqrt(128)

    // Q B-operand frags: lane holds Q[q0+l31][kst*16 + h*8 + j]
    v8s qf[8];
    {
        const float* qp = Qg + base + (size_t)(q0 + l31) * D + h * 8;
        #pragma unroll
        for (int kst = 0; kst < 8; ++kst) {
            float4 a = *(const float4*)(qp + kst * 16);
            float4 b = *(const float4*)(qp + kst * 16 + 4);
            union { u32 w[4]; v8s v; } qu;
            qu.w[0] = cvtpk(a.x * SCALE, a.y * SCALE);
            qu.w[1] = cvtpk(a.z * SCALE, a.w * SCALE);
            qu.w[2] = cvtpk(b.x * SCALE, b.y * SCALE);
            qu.w[3] = cvtpk(b.z * SCALE, b.w * SCALE);
            qf[kst] = qu.v;
        }
    }

    v16f o[4];
    #pragma unroll
    for (int i = 0; i < 4; ++i)
        #pragma unroll
        for (int r = 0; r < 16; ++r) o[i][r] = 0.f;
    float m_run = -1e30f, l_run = 0.f;

    auto stage = [&](int buf, int kv0) {
        #pragma unroll
        for (int i = 0; i < 2; ++i) {           // K: chunk = 4 rows x 256B
            int ch = wave * 2 + i;
            int row = ch * 4 + (lane >> 4);
            int sl = lane & 15;
            const short* src = Kb + base + (size_t)(kv0 + row) * D + ((sl ^ (row & 7)) << 3);
            gload_lds16(src, &Ks[buf][ch * 512]);
        }
        #pragma unroll
        for (int i = 0; i < 2; ++i) {           // V: chunk = 8 d-rows x 128B
            int ch = wave * 2 + i;
            int d = ch * 8 + (lane >> 3);
            int sl = lane & 7;
            const short* src = Vb + base + (size_t)d * S + kv0 + ((sl ^ (d & 7)) << 3);
            gload_lds16(src, &Vt[buf][ch * 512]);
        }
    };

    stage(0, 0);
    __syncthreads();

    for (int it = 0; it < NT; ++it) {
        const int c = it & 1;
        if (it + 1 < NT) stage(c ^ 1, (it + 1) * KVBLK);   // prefetch under compute

        const short* ks = &Ks[c][0];
        const short* vt = &Vt[c][0];

        // ---- QK^T swapped: S^T[kv][q], C: col=l31=q, row=kv_local
        v16f s0, s1;
        #pragma unroll
        for (int r = 0; r < 16; ++r) { s0[r] = 0.f; s1[r] = 0.f; }
        __builtin_amdgcn_s_setprio(1);
        #pragma unroll
        for (int kst = 0; kst < 8; ++kst) {
            int sl = (kst * 2 + h) ^ (l31 & 7);
            v8s k0 = *(const v8s*)(&ks[l31 * D + sl * 8]);
            s0 = __builtin_amdgcn_mfma_f32_32x32x16_bf16(k0, qf[kst], s0, 0, 0, 0);
            v8s k1 = *(const v8s*)(&ks[(32 + l31) * D + sl * 8]);
            s1 = __builtin_amdgcn_mfma_f32_32x32x16_bf16(k1, qf[kst], s1, 0, 0, 0);
        }
        __builtin_amdgcn_s_setprio(0);

        // ---- online softmax: q = l31 is lane-local; rows split lane vs lane^32
        float tm = s0[0];
        #pragma unroll
        for (int r = 1; r < 16; ++r) tm = fmaxf(tm, s0[r]);
        #pragma unroll
        for (int r = 0; r < 16; ++r) tm = fmaxf(tm, s1[r]);
        tm = fmaxf(tm, __shfl_xor(tm, 32));

        bool skip = __all(tm <= m_run + 8.f);     // T13 defer-max, THR=8
        if (!skip) {
            float m_new = fmaxf(m_run, tm);
            float alpha = exp2f(m_run - m_new);
            #pragma unroll
            for (int i = 0; i < 4; ++i)
                #pragma unroll
                for (int r = 0; r < 16; ++r) o[i][r] *= alpha;
            l_run *= alpha;
            m_run = m_new;
        }
        float ts = 0.f;
        #pragma unroll
        for (int r = 0; r < 16; ++r) { s0[r] = exp2f(s0[r] - m_run); ts += s0[r]; }
        #pragma unroll
        for (int r = 0; r < 16; ++r) { s1[r] = exp2f(s1[r] - m_run); ts += s1[r]; }
        ts += __shfl_xor(ts, 32);
        l_run += ts;

        // ---- T12: P -> bf16 B-operand in-register (cvt_pk + permlane32_swap)
        v8s pf[4];
        #pragma unroll
        for (int ks2 = 0; ks2 < 4; ++ks2) {
            const v16f& P = (ks2 < 2) ? s0 : s1;
            int rb = (ks2 & 1) * 8;
            u32 a  = cvtpk(P[rb + 0], P[rb + 1]);
            u32 b  = cvtpk(P[rb + 2], P[rb + 3]);
            u32 cc = cvtpk(P[rb + 4], P[rb + 5]);
            u32 dd = cvtpk(P[rb + 6], P[rb + 7]);
            asm volatile("v_permlane32_swap_b32 %0, %1" : "+v"(a), "+v"(cc));
            asm volatile("v_permlane32_swap_b32 %0, %1" : "+v"(b), "+v"(dd));
            union { u32 w[4]; v8s v; } pu;
            pu.w[0] = a; pu.w[1] = b; pu.w[2] = cc; pu.w[3] = dd;
            pf[ks2] = pu.v;
        }

        // ---- PV: O^T += V^T · P^T
        __builtin_amdgcn_s_setprio(1);
        #pragma unroll
        for (int dt = 0; dt < 4; ++dt) {
            int d = dt * 32 + l31;
            #pragma unroll
            for (int ks2 = 0; ks2 < 4; ++ks2) {
                int sl = (ks2 * 2 + h) ^ (d & 7);
                v8s vf = *(const v8s*)(&vt[d * KVBLK + sl * 8]);
                o[dt] = __builtin_amdgcn_mfma_f32_32x32x16_bf16(vf, pf[ks2], o[dt], 0, 0, 0);
            }
        }
        __builtin_amdgcn_s_setprio(0);

        __syncthreads();   // drains prefetch + buffer-reuse barrier
    }

    // ---- epilogue: O[q][d] = o / l_run; regs g*4..g*4+3 are 4 consecutive d
    float inv = 1.f / l_run;
    float* op = Og + base + (size_t)(q0 + l31) * D;
    #pragma unroll
    for (int dt = 0; dt < 4; ++dt)
        #pragma unroll
        for (int g = 0; g < 4; ++g) {
            float4 w;
            w.x = o[dt][g * 4 + 0] * inv; w.y = o[dt][g * 4 + 1] * inv;
            w.z = o[dt][g * 4 + 2] * inv; w.w = o[dt][g * 4 + 3] * inv;
            *(float4*)(op + dt * 32 + g * 8 + 4 * h) = w;
        }
}

extern "C" void kernel_launch(void* const* d_in, const int* in_sizes, int n_in,
                              void* d_out, int out_size, void* d_ws, size_t ws_size,
                              hipStream_t stream) {
    const float* Q = (const float*)d_in[0];
    const float* K = (const float*)d_in[1];
    const float* V = (const float*)d_in[2];
    float* O = (float*)d_out;

    short* Kb  = (short*)d_ws;                 // 33.55 MB
    short* VtG = Kb + (size_t)BH * S * D;      // 33.55 MB

    prep_kernel<<<dim3(NT, BH), dim3(256), 0, stream>>>(K, V, Kb, VtG);
    fattn_kernel<<<dim3(BH * 8), dim3(512), 0, stream>>>(Q, Kb, VtG, O);
}